// Round 1
// baseline (11947.914 us; speedup 1.0000x reference)
//
#include <hip/hip_runtime.h>

#define N_NODES 20000
#define N_EDGES 320000
#define N_GRAPHS 64
#define HID 256

// ---------------- per-node A/B precompute ----------------
// A = x @ (w1_top - w1_bot) + b1  ;  B = x @ w1_bot
template <int DIN>
__global__ __launch_bounds__(256) void node_ab_kernel(
    const float* __restrict__ x,
    const float* __restrict__ w1, const float* __restrict__ b1,
    float* __restrict__ A, float* __restrict__ B) {
  __shared__ float xs[32 * DIN];
  const int node0 = blockIdx.x * 32;
  const int j = threadIdx.x;
  for (int t = threadIdx.x; t < 32 * DIN; t += 256) {
    int r = t / DIN, c = t - r * DIN;
    int node = node0 + r;
    xs[t] = (node < N_NODES) ? x[node * DIN + c] : 0.f;
  }
  __syncthreads();
  float accA[32], accB[32];
#pragma unroll
  for (int i = 0; i < 32; i++) { accA[i] = 0.f; accB[i] = 0.f; }
  for (int k = 0; k < DIN; k++) {
    float wt = w1[k * HID + j];
    float wb = w1[(k + DIN) * HID + j];
    float wa = wt - wb;
#pragma unroll
    for (int i = 0; i < 32; i++) {
      float xv = xs[i * DIN + k];
      accA[i] = fmaf(xv, wa, accA[i]);
      accB[i] = fmaf(xv, wb, accB[i]);
    }
  }
  float bj = b1[j];
  for (int i = 0; i < 32; i++) {
    int node = node0 + i;
    if (node < N_NODES) {
      A[node * HID + j] = accA[i] + bj;
      B[node * HID + j] = accB[i];
    }
  }
}

// ---------------- edge MLP + max-aggregate ----------------
// per edge: h = relu(A[dst] + B[src]); out = h @ w2 + b2; atomicMax into agg[dst]
__global__ __launch_bounds__(256) void edge_mlp_kernel(
    const int* __restrict__ ei,
    const float* __restrict__ A, const float* __restrict__ Bm,
    const float* __restrict__ w2, const float* __restrict__ b2,
    unsigned int* __restrict__ agg) {
  __shared__ float hs[64][257];   // [edge][k], +1 pad -> conflict-free both phases
  __shared__ int sdst[64];
  const int e0 = blockIdx.x * 64;
  const int tid = threadIdx.x;
  if (tid < 64) sdst[tid] = ei[N_EDGES + e0 + tid];
  __syncthreads();
  // gather + relu: one edge per rep, k = tid (coalesced 1KB rows)
  for (int rep = 0; rep < 64; rep++) {
    int s = ei[e0 + rep];
    int d = sdst[rep];
    float v = A[d * HID + tid] + Bm[s * HID + tid];
    hs[rep][tid] = fmaxf(v, 0.f);
  }
  __syncthreads();
  // register-tiled GEMM: each thread = 4 edges x 16 cols
  const int j0 = (tid & 15) << 4;
  const int eb = (tid >> 4) << 2;
  float acc[4][16];
#pragma unroll
  for (int i = 0; i < 4; i++)
#pragma unroll
    for (int jj = 0; jj < 16; jj++) acc[i][jj] = 0.f;

  for (int k = 0; k < HID; k++) {
    const float4* wrow = (const float4*)(w2 + k * HID + j0);
    float wv[16];
    *(float4*)(wv + 0)  = wrow[0];
    *(float4*)(wv + 4)  = wrow[1];
    *(float4*)(wv + 8)  = wrow[2];
    *(float4*)(wv + 12) = wrow[3];
    float hv[4];
#pragma unroll
    for (int i = 0; i < 4; i++) hv[i] = hs[eb + i][k];
#pragma unroll
    for (int i = 0; i < 4; i++)
#pragma unroll
      for (int jj = 0; jj < 16; jj++)
        acc[i][jj] = fmaf(hv[i], wv[jj], acc[i][jj]);
  }

  float bv[16];
#pragma unroll
  for (int jj = 0; jj < 16; jj++) bv[jj] = b2[j0 + jj];
#pragma unroll
  for (int i = 0; i < 4; i++) {
    int d = sdst[eb + i];
    unsigned int* rowp = agg + (size_t)d * HID + j0;
#pragma unroll
    for (int jj = 0; jj < 16; jj++) {
      float v = acc[i][jj] + bv[jj];
      unsigned int bits = __float_as_uint(v);
      unsigned int enc = (bits & 0x80000000u) ? ~bits : (bits | 0x80000000u);
      atomicMax(rowp + jj, enc);
    }
  }
}

// ---------------- decode monotone-uint -> float ----------------
__global__ __launch_bounds__(256) void decode_kernel(
    const unsigned int* __restrict__ agg, float* __restrict__ X) {
  int i = blockIdx.x * 256 + threadIdx.x;
  unsigned int u = agg[i];
  float f;
  if (u == 0u) {
    f = 0.f;  // no in-edges -> 0 (matches where(isfinite, agg, 0))
  } else {
    unsigned int bits = (u & 0x80000000u) ? (u ^ 0x80000000u) : ~u;
    f = __uint_as_float(bits);
  }
  X[i] = f;
}

// ---------------- per-graph mean/max pooling ----------------
__device__ __forceinline__ int lower_bound_i(const int* __restrict__ arr, int n, int val) {
  int lo = 0, hi = n;
  while (lo < hi) {
    int mid = (lo + hi) >> 1;
    if (arr[mid] < val) lo = mid + 1; else hi = mid;
  }
  return lo;
}

__global__ __launch_bounds__(256) void pool_kernel(
    const float* __restrict__ X, const int* __restrict__ batch,
    float* __restrict__ GP) {
  const int g = blockIdx.x;
  const int j = threadIdx.x;
  int s = lower_bound_i(batch, N_NODES, g);
  int e = lower_bound_i(batch, N_NODES, g + 1);
  float sum = 0.f, mx = -INFINITY;
  for (int i = s; i < e; i++) {
    float v = X[(size_t)i * HID + j];
    sum += v;
    mx = fmaxf(mx, v);
  }
  int cnt = e - s;
  GP[g * (2 * HID) + j] = sum / fmaxf((float)cnt, 1.f);
  GP[g * (2 * HID) + HID + j] = (cnt > 0) ? mx : 0.f;
}

// ---------------- graph-level MLP head ----------------
__global__ __launch_bounds__(256) void mlp_kernel(
    const float* __restrict__ GP,
    const float* __restrict__ wc1, const float* __restrict__ bc1,
    const float* __restrict__ wc2, const float* __restrict__ bc2,
    const float* __restrict__ wc3, const float* __restrict__ bc3,
    float* __restrict__ out) {
  const int g = blockIdx.x;
  const int tid = threadIdx.x;
  __shared__ float gs[2 * HID];
  __shared__ float h1[HID];
  __shared__ float h2[64];
  gs[tid] = GP[g * (2 * HID) + tid];
  gs[tid + HID] = GP[g * (2 * HID) + HID + tid];
  __syncthreads();
  float acc = bc1[tid];
  for (int k = 0; k < 2 * HID; k++) acc = fmaf(gs[k], wc1[k * HID + tid], acc);
  h1[tid] = fmaxf(acc, 0.f);
  __syncthreads();
  if (tid < 64) {
    float a2 = bc2[tid];
    for (int k = 0; k < HID; k++) a2 = fmaf(h1[k], wc2[k * 64 + tid], a2);
    h2[tid] = fmaxf(a2, 0.f);
  }
  __syncthreads();
  if (tid == 0) {
    float a3 = bc3[0];
    for (int k = 0; k < 64; k++) a3 = fmaf(h2[k], wc3[k], a3);
    out[g] = a3;
  }
}

extern "C" void kernel_launch(void* const* d_in, const int* in_sizes, int n_in,
                              void* d_out, int out_size, void* d_ws, size_t ws_size,
                              hipStream_t stream) {
  const float* x      = (const float*)d_in[0];
  const int*   ei     = (const int*)d_in[1];
  const int*   batch  = (const int*)d_in[2];
  const float* w1[3]  = {(const float*)d_in[3], (const float*)d_in[7],  (const float*)d_in[11]};
  const float* b1[3]  = {(const float*)d_in[4], (const float*)d_in[8],  (const float*)d_in[12]};
  const float* w2[3]  = {(const float*)d_in[5], (const float*)d_in[9],  (const float*)d_in[13]};
  const float* b2[3]  = {(const float*)d_in[6], (const float*)d_in[10], (const float*)d_in[14]};
  const float* wc1 = (const float*)d_in[15];
  const float* bc1 = (const float*)d_in[16];
  const float* wc2 = (const float*)d_in[17];
  const float* bc2 = (const float*)d_in[18];
  const float* wc3 = (const float*)d_in[19];
  const float* bc3 = (const float*)d_in[20];
  float* out = (float*)d_out;

  char* ws = (char*)d_ws;
  size_t off = 0;
  auto walloc = [&](size_t bytes) -> void* {
    void* p = ws + off;
    off += (bytes + 255) & ~(size_t)255;
    return p;
  };
  const size_t nh_bytes = (size_t)N_NODES * HID * sizeof(float);
  float*        A   = (float*)walloc(nh_bytes);
  float*        Bm  = (float*)walloc(nh_bytes);
  float*        X   = (float*)walloc(nh_bytes);
  unsigned int* AGG = (unsigned int*)walloc(nh_bytes);
  float*        GP  = (float*)walloc((size_t)N_GRAPHS * 2 * HID * sizeof(float));
  (void)ws_size; (void)in_sizes; (void)n_in; (void)out_size;

  for (int l = 0; l < 3; l++) {
    if (l == 0)
      node_ab_kernel<56><<<N_NODES / 32, 256, 0, stream>>>(x, w1[0], b1[0], A, Bm);
    else
      node_ab_kernel<256><<<N_NODES / 32, 256, 0, stream>>>(X, w1[l], b1[l], A, Bm);
    hipMemsetAsync(AGG, 0, nh_bytes, stream);
    edge_mlp_kernel<<<N_EDGES / 64, 256, 0, stream>>>(ei, A, Bm, w2[l], b2[l], AGG);
    decode_kernel<<<(N_NODES * HID) / 256, 256, 0, stream>>>(AGG, X);
  }
  pool_kernel<<<N_GRAPHS, 256, 0, stream>>>(X, batch, GP);
  mlp_kernel<<<N_GRAPHS, 256, 0, stream>>>(GP, wc1, bc1, wc2, bc2, wc3, bc3, out);
}

// Round 2
// 4140.505 us; speedup vs baseline: 2.8856x; 2.8856x over previous
//
#include <hip/hip_runtime.h>

#define N_NODES 20000
#define N_EDGES 320000
#define N_GRAPHS 64
#define HID 256

// ---------------- CSR build (once per launch, reused for all 3 layers) ----
__global__ __launch_bounds__(256) void hist_kernel(const int* __restrict__ ei,
                                                   int* __restrict__ deg) {
  int e = blockIdx.x * 256 + threadIdx.x;
  if (e < N_EDGES) atomicAdd(&deg[ei[N_EDGES + e]], 1);
}

// single-block exclusive scan of deg[N_NODES] -> cursor
__global__ __launch_bounds__(256) void scan_kernel(const int* __restrict__ deg,
                                                   int* __restrict__ cursor) {
  __shared__ int part[256];
  const int tid = threadIdx.x;
  const int CH = (N_NODES + 255) / 256;
  int s = tid * CH;
  int e = s + CH; if (e > N_NODES) e = N_NODES; if (s > N_NODES) s = N_NODES;
  int sum = 0;
  for (int i = s; i < e; i++) sum += deg[i];
  part[tid] = sum;
  __syncthreads();
  for (int off = 1; off < 256; off <<= 1) {
    int v = (tid >= off) ? part[tid - off] : 0;
    __syncthreads();
    part[tid] += v;
    __syncthreads();
  }
  int prefix = (tid == 0) ? 0 : part[tid - 1];
  for (int i = s; i < e; i++) {
    cursor[i] = prefix;
    prefix += deg[i];
  }
}

__global__ __launch_bounds__(256) void scatter_kernel(const int* __restrict__ ei,
                                                      int* __restrict__ cursor,
                                                      int* __restrict__ csr_src,
                                                      int* __restrict__ csr_dst) {
  int e = blockIdx.x * 256 + threadIdx.x;
  if (e < N_EDGES) {
    int s = ei[e], d = ei[N_EDGES + e];
    int pos = atomicAdd(&cursor[d], 1);
    csr_src[pos] = s;
    csr_dst[pos] = d;
  }
}

// ---------------- per-node A/B precompute ----------------
// A = x @ (w1_top - w1_bot) + b1  ;  B = x @ w1_bot
template <int DIN>
__global__ __launch_bounds__(256) void node_ab_kernel(
    const float* __restrict__ x,
    const float* __restrict__ w1, const float* __restrict__ b1,
    float* __restrict__ A, float* __restrict__ B) {
  __shared__ float xs[32 * DIN];
  const int node0 = blockIdx.x * 32;
  const int j = threadIdx.x;
  for (int t = threadIdx.x; t < 32 * DIN; t += 256) {
    int r = t / DIN, c = t - r * DIN;
    int node = node0 + r;
    xs[t] = (node < N_NODES) ? x[node * DIN + c] : 0.f;
  }
  __syncthreads();
  float accA[32], accB[32];
#pragma unroll
  for (int i = 0; i < 32; i++) { accA[i] = 0.f; accB[i] = 0.f; }
  for (int k = 0; k < DIN; k++) {
    float wt = w1[k * HID + j];
    float wb = w1[(k + DIN) * HID + j];
    float wa = wt - wb;
#pragma unroll
    for (int i = 0; i < 32; i++) {
      float xv = xs[i * DIN + k];
      accA[i] = fmaf(xv, wa, accA[i]);
      accB[i] = fmaf(xv, wb, accB[i]);
    }
  }
  float bj = b1[j];
  for (int i = 0; i < 32; i++) {
    int node = node0 + i;
    if (node < N_NODES) {
      A[node * HID + j] = accA[i] + bj;
      B[node * HID + j] = accB[i];
    }
  }
}

__device__ __forceinline__ unsigned int enc_f32(float v) {
  unsigned int bits = __float_as_uint(v);
  return (bits & 0x80000000u) ? ~bits : (bits | 0x80000000u);
}

// ---------------- edge MLP + segmented max-aggregate (CSR order) ----------
// per edge: h = relu(A[dst] + B[src]); out = h @ w2 + b2
// edges sorted by dst -> segmented max per 64-edge tile; only tile-boundary
// segments need atomicMax, interior segments plain-store.
__global__ __launch_bounds__(256) void edge_mlp_csr_kernel(
    const int* __restrict__ csr_src, const int* __restrict__ csr_dst,
    const float* __restrict__ A, const float* __restrict__ Bm,
    const float* __restrict__ w2, const float* __restrict__ b2,
    unsigned int* __restrict__ agg) {
  __shared__ float hs[64][257];   // [edge][k], +1 pad -> conflict-free
  __shared__ int sdst[64];
  __shared__ int ssrc[64];
  const int e0 = blockIdx.x * 64;
  const int tid = threadIdx.x;
  if (tid < 64) {
    sdst[tid] = csr_dst[e0 + tid];
    ssrc[tid] = csr_src[e0 + tid];
  }
  __syncthreads();
  // gather + relu: one edge per rep, k = tid (coalesced 1KB rows)
  for (int rep = 0; rep < 64; rep++) {
    float v = A[(size_t)sdst[rep] * HID + tid] + Bm[(size_t)ssrc[rep] * HID + tid];
    hs[rep][tid] = fmaxf(v, 0.f);
  }
  __syncthreads();
  // register-tiled GEMM: each thread = 4 edges x 16 cols
  const int j0 = (tid & 15) << 4;
  const int eb = (tid >> 4) << 2;
  float acc[4][16];
#pragma unroll
  for (int i = 0; i < 4; i++)
#pragma unroll
    for (int jj = 0; jj < 16; jj++) acc[i][jj] = 0.f;

  for (int k = 0; k < HID; k++) {
    const float4* wrow = (const float4*)(w2 + k * HID + j0);
    float wv[16];
    *(float4*)(wv + 0)  = wrow[0];
    *(float4*)(wv + 4)  = wrow[1];
    *(float4*)(wv + 8)  = wrow[2];
    *(float4*)(wv + 12) = wrow[3];
    float hv[4];
#pragma unroll
    for (int i = 0; i < 4; i++) hv[i] = hs[eb + i][k];
#pragma unroll
    for (int i = 0; i < 4; i++)
#pragma unroll
      for (int jj = 0; jj < 16; jj++)
        acc[i][jj] = fmaf(hv[i], wv[jj], acc[i][jj]);
  }
  __syncthreads();
  // write per-edge outputs (+bias) back into hs
  float bv[16];
#pragma unroll
  for (int jj = 0; jj < 16; jj++) bv[jj] = b2[j0 + jj];
#pragma unroll
  for (int i = 0; i < 4; i++)
#pragma unroll
    for (int jj = 0; jj < 16; jj++)
      hs[eb + i][j0 + jj] = acc[i][jj] + bv[jj];
  __syncthreads();
  // segmented max along the 64 edges; thread = one output column
  const int j = tid;
  int prevd = sdst[0];
  int segstart = 0;
  float run = -INFINITY;
  for (int e = 0; e < 64; e++) {
    int d = sdst[e];           // block-uniform branch (shared mem)
    if (d != prevd) {
      unsigned int enc = enc_f32(run);
      unsigned int* p = agg + (size_t)prevd * HID + j;
      if (segstart == 0) atomicMax(p, enc);  // open-left segment
      else *p = enc;                          // interior: exclusive to this tile
      run = -INFINITY;
      segstart = e;
      prevd = d;
    }
    run = fmaxf(run, hs[e][j]);
  }
  // last segment: always open-right
  atomicMax(agg + (size_t)prevd * HID + j, enc_f32(run));
}

// ---------------- decode monotone-uint -> float ----------------
__global__ __launch_bounds__(256) void decode_kernel(
    const unsigned int* __restrict__ agg, float* __restrict__ X) {
  int i = blockIdx.x * 256 + threadIdx.x;
  unsigned int u = agg[i];
  float f;
  if (u == 0u) {
    f = 0.f;  // no in-edges -> 0 (matches where(isfinite, agg, 0))
  } else {
    unsigned int bits = (u & 0x80000000u) ? (u ^ 0x80000000u) : ~u;
    f = __uint_as_float(bits);
  }
  X[i] = f;
}

// ---------------- per-graph mean/max pooling ----------------
__device__ __forceinline__ int lower_bound_i(const int* __restrict__ arr, int n, int val) {
  int lo = 0, hi = n;
  while (lo < hi) {
    int mid = (lo + hi) >> 1;
    if (arr[mid] < val) lo = mid + 1; else hi = mid;
  }
  return lo;
}

__global__ __launch_bounds__(256) void pool_kernel(
    const float* __restrict__ X, const int* __restrict__ batch,
    float* __restrict__ GP) {
  const int g = blockIdx.x;
  const int j = threadIdx.x;
  int s = lower_bound_i(batch, N_NODES, g);
  int e = lower_bound_i(batch, N_NODES, g + 1);
  float sum = 0.f, mx = -INFINITY;
  for (int i = s; i < e; i++) {
    float v = X[(size_t)i * HID + j];
    sum += v;
    mx = fmaxf(mx, v);
  }
  int cnt = e - s;
  GP[g * (2 * HID) + j] = sum / fmaxf((float)cnt, 1.f);
  GP[g * (2 * HID) + HID + j] = (cnt > 0) ? mx : 0.f;
}

// ---------------- graph-level MLP head ----------------
__global__ __launch_bounds__(256) void mlp_kernel(
    const float* __restrict__ GP,
    const float* __restrict__ wc1, const float* __restrict__ bc1,
    const float* __restrict__ wc2, const float* __restrict__ bc2,
    const float* __restrict__ wc3, const float* __restrict__ bc3,
    float* __restrict__ out) {
  const int g = blockIdx.x;
  const int tid = threadIdx.x;
  __shared__ float gs[2 * HID];
  __shared__ float h1[HID];
  __shared__ float h2[64];
  gs[tid] = GP[g * (2 * HID) + tid];
  gs[tid + HID] = GP[g * (2 * HID) + HID + tid];
  __syncthreads();
  float acc = bc1[tid];
  for (int k = 0; k < 2 * HID; k++) acc = fmaf(gs[k], wc1[k * HID + tid], acc);
  h1[tid] = fmaxf(acc, 0.f);
  __syncthreads();
  if (tid < 64) {
    float a2 = bc2[tid];
    for (int k = 0; k < HID; k++) a2 = fmaf(h1[k], wc2[k * 64 + tid], a2);
    h2[tid] = fmaxf(a2, 0.f);
  }
  __syncthreads();
  if (tid == 0) {
    float a3 = bc3[0];
    for (int k = 0; k < 64; k++) a3 = fmaf(h2[k], wc3[k], a3);
    out[g] = a3;
  }
}

extern "C" void kernel_launch(void* const* d_in, const int* in_sizes, int n_in,
                              void* d_out, int out_size, void* d_ws, size_t ws_size,
                              hipStream_t stream) {
  const float* x      = (const float*)d_in[0];
  const int*   ei     = (const int*)d_in[1];
  const int*   batch  = (const int*)d_in[2];
  const float* w1[3]  = {(const float*)d_in[3], (const float*)d_in[7],  (const float*)d_in[11]};
  const float* b1[3]  = {(const float*)d_in[4], (const float*)d_in[8],  (const float*)d_in[12]};
  const float* w2[3]  = {(const float*)d_in[5], (const float*)d_in[9],  (const float*)d_in[13]};
  const float* b2[3]  = {(const float*)d_in[6], (const float*)d_in[10], (const float*)d_in[14]};
  const float* wc1 = (const float*)d_in[15];
  const float* bc1 = (const float*)d_in[16];
  const float* wc2 = (const float*)d_in[17];
  const float* bc2 = (const float*)d_in[18];
  const float* wc3 = (const float*)d_in[19];
  const float* bc3 = (const float*)d_in[20];
  float* out = (float*)d_out;

  char* ws = (char*)d_ws;
  size_t off = 0;
  auto walloc = [&](size_t bytes) -> void* {
    void* p = ws + off;
    off += (bytes + 255) & ~(size_t)255;
    return p;
  };
  const size_t nh_bytes = (size_t)N_NODES * HID * sizeof(float);
  float*        A       = (float*)walloc(nh_bytes);
  float*        Bm      = (float*)walloc(nh_bytes);
  float*        X       = (float*)walloc(nh_bytes);
  unsigned int* AGG     = (unsigned int*)walloc(nh_bytes);
  float*        GP      = (float*)walloc((size_t)N_GRAPHS * 2 * HID * sizeof(float));
  int*          deg     = (int*)walloc((size_t)N_NODES * sizeof(int));
  int*          cursor  = (int*)walloc((size_t)N_NODES * sizeof(int));
  int*          csr_src = (int*)walloc((size_t)N_EDGES * sizeof(int));
  int*          csr_dst = (int*)walloc((size_t)N_EDGES * sizeof(int));
  (void)ws_size; (void)in_sizes; (void)n_in; (void)out_size;

  // ---- build CSR (by dst) once; max-agg is order-independent so the
  // nondeterministic within-bucket scatter order does not affect output ----
  hipMemsetAsync(deg, 0, N_NODES * sizeof(int), stream);
  hist_kernel<<<(N_EDGES + 255) / 256, 256, 0, stream>>>(ei, deg);
  scan_kernel<<<1, 256, 0, stream>>>(deg, cursor);
  scatter_kernel<<<(N_EDGES + 255) / 256, 256, 0, stream>>>(ei, cursor, csr_src, csr_dst);

  for (int l = 0; l < 3; l++) {
    if (l == 0)
      node_ab_kernel<56><<<N_NODES / 32, 256, 0, stream>>>(x, w1[0], b1[0], A, Bm);
    else
      node_ab_kernel<256><<<N_NODES / 32, 256, 0, stream>>>(X, w1[l], b1[l], A, Bm);
    hipMemsetAsync(AGG, 0, nh_bytes, stream);
    edge_mlp_csr_kernel<<<N_EDGES / 64, 256, 0, stream>>>(csr_src, csr_dst, A, Bm, w2[l], b2[l], AGG);
    decode_kernel<<<(N_NODES * HID) / 256, 256, 0, stream>>>(AGG, X);
  }
  pool_kernel<<<N_GRAPHS, 256, 0, stream>>>(X, batch, GP);
  mlp_kernel<<<N_GRAPHS, 256, 0, stream>>>(GP, wc1, bc1, wc2, bc2, wc3, bc3, out);
}

// Round 3
// 1480.359 us; speedup vs baseline: 8.0710x; 2.7970x over previous
//
#include <hip/hip_runtime.h>

#define N_NODES 20000
#define N_EDGES 320000
#define N_GRAPHS 64
#define HID 256

typedef __attribute__((ext_vector_type(8))) short bf16x8;
typedef __attribute__((ext_vector_type(4))) float f32x4;

// ---------------- CSR build (once per launch, reused for all 3 layers) ----
__global__ __launch_bounds__(256) void hist_kernel(const int* __restrict__ ei,
                                                   int* __restrict__ deg) {
  int e = blockIdx.x * 256 + threadIdx.x;
  if (e < N_EDGES) atomicAdd(&deg[ei[N_EDGES + e]], 1);
}

__global__ __launch_bounds__(256) void scan_kernel(const int* __restrict__ deg,
                                                   int* __restrict__ cursor) {
  __shared__ int part[256];
  const int tid = threadIdx.x;
  const int CH = (N_NODES + 255) / 256;
  int s = tid * CH;
  int e = s + CH; if (e > N_NODES) e = N_NODES; if (s > N_NODES) s = N_NODES;
  int sum = 0;
  for (int i = s; i < e; i++) sum += deg[i];
  part[tid] = sum;
  __syncthreads();
  for (int off = 1; off < 256; off <<= 1) {
    int v = (tid >= off) ? part[tid - off] : 0;
    __syncthreads();
    part[tid] += v;
    __syncthreads();
  }
  int prefix = (tid == 0) ? 0 : part[tid - 1];
  for (int i = s; i < e; i++) {
    cursor[i] = prefix;
    prefix += deg[i];
  }
}

__global__ __launch_bounds__(256) void scatter_kernel(const int* __restrict__ ei,
                                                      int* __restrict__ cursor,
                                                      int* __restrict__ csr_src,
                                                      int* __restrict__ csr_dst) {
  int e = blockIdx.x * 256 + threadIdx.x;
  if (e < N_EDGES) {
    int s = ei[e], d = ei[N_EDGES + e];
    int pos = atomicAdd(&cursor[d], 1);
    csr_src[pos] = s;
    csr_dst[pos] = d;
  }
}

// ---------------- helpers ----------------
__device__ __forceinline__ unsigned short bf16_rne(float f) {
  unsigned u = __float_as_uint(f);
  u = u + 0x7FFFu + ((u >> 16) & 1u);
  return (unsigned short)(u >> 16);
}

__device__ __forceinline__ unsigned int enc_f32(float v) {
  unsigned int bits = __float_as_uint(v);
  return (bits & 0x80000000u) ? ~bits : (bits | 0x80000000u);
}

// ---------------- per-node A/B precompute ----------------
// A = x @ (w1_top - w1_bot) + b1  ;  B = x @ w1_bot
template <int DIN>
__global__ __launch_bounds__(256) void node_ab_kernel(
    const float* __restrict__ x,
    const float* __restrict__ w1, const float* __restrict__ b1,
    float* __restrict__ A, float* __restrict__ B) {
  __shared__ float xs[32 * DIN];
  const int node0 = blockIdx.x * 32;
  const int j = threadIdx.x;
  for (int t = threadIdx.x; t < 32 * DIN; t += 256) {
    int r = t / DIN, c = t - r * DIN;
    int node = node0 + r;
    xs[t] = (node < N_NODES) ? x[node * DIN + c] : 0.f;
  }
  __syncthreads();
  float accA[32], accB[32];
#pragma unroll
  for (int i = 0; i < 32; i++) { accA[i] = 0.f; accB[i] = 0.f; }
  for (int k = 0; k < DIN; k++) {
    float wt = w1[k * HID + j];
    float wb = w1[(k + DIN) * HID + j];
    float wa = wt - wb;
#pragma unroll
    for (int i = 0; i < 32; i++) {
      float xv = xs[i * DIN + k];
      accA[i] = fmaf(xv, wa, accA[i]);
      accB[i] = fmaf(xv, wb, accB[i]);
    }
  }
  float bj = b1[j];
  for (int i = 0; i < 32; i++) {
    int node = node0 + i;
    if (node < N_NODES) {
      A[node * HID + j] = accA[i] + bj;
      B[node * HID + j] = accB[i];
    }
  }
}

// ---------------- w2 transpose + hi/lo bf16 split (per layer, tiny) ------
__global__ __launch_bounds__(256) void conv_w2_kernel(
    const float* __restrict__ w2,
    unsigned short* __restrict__ w2t_hi, unsigned short* __restrict__ w2t_lo) {
  int j = blockIdx.x;    // output col
  int k = threadIdx.x;   // k index
  float v = w2[k * HID + j];
  unsigned short hi = bf16_rne(v);
  float rem = v - __uint_as_float(((unsigned)hi) << 16);
  w2t_hi[j * HID + k] = hi;                 // [j][k], coalesced in k
  w2t_lo[j * HID + k] = bf16_rne(rem);
}

// ---------------- edge MLP (MFMA, hi/lo split) + segmented max ----------
// OUT[e][j] = relu(A[dst]+B[src]) @ w2 + b2 ; segmented max by dst (CSR order)
__global__ __launch_bounds__(256, 2) void edge_mfma_kernel(
    const int* __restrict__ csr_src, const int* __restrict__ csr_dst,
    const float* __restrict__ A, const float* __restrict__ Bm,
    const unsigned short* __restrict__ w2t_hi,
    const unsigned short* __restrict__ w2t_lo,
    const float* __restrict__ b2,
    unsigned int* __restrict__ agg) {
  // sm layout: phase 1: hs_hi bf16[64][256] @0 (32KB), hs_lo @32768 (32KB)
  //            phase 2 (after barrier): OUT f32[64][256] @0 (64KB)
  __shared__ char sm[65536];
  __shared__ int sdst[64];
  __shared__ int ssrc[64];
  const int tid = threadIdx.x;
  const int e0 = blockIdx.x * 64;
  if (tid < 64) { sdst[tid] = csr_dst[e0 + tid]; ssrc[tid] = csr_src[e0 + tid]; }
  __syncthreads();

  // ---- gather + relu + hi/lo split into LDS (row-XOR swizzle) ----
  for (int rep = 0; rep < 64; rep++) {
    int s = ssrc[rep], d = sdst[rep];
    float v = A[(size_t)d * HID + tid] + Bm[(size_t)s * HID + tid];
    v = fmaxf(v, 0.f);
    unsigned short hi = bf16_rne(v);
    float rem = v - __uint_as_float(((unsigned)hi) << 16);
    unsigned short lo = bf16_rne(rem);
    int byte = rep * 512 + ((tid * 2) ^ ((rep & 7) << 4));
    *(unsigned short*)(sm + byte) = hi;
    *(unsigned short*)(sm + 32768 + byte) = lo;
  }
  __syncthreads();

  // ---- MFMA: wave w computes OUT[0:64][w*64 : w*64+64] ----
  const int lane = tid & 63;
  const int wid = tid >> 6;
  const int nbase = wid * 64;
  const int lr = lane & 15;   // A row / B col / C col component
  const int lg = lane >> 4;   // k-chunk group (8 elems each)
  f32x4 acc[4][4];
#pragma unroll
  for (int mt = 0; mt < 4; mt++)
#pragma unroll
    for (int nt = 0; nt < 4; nt++) acc[mt][nt] = (f32x4){0.f, 0.f, 0.f, 0.f};

#pragma unroll
  for (int ks = 0; ks < 8; ks++) {
    const int kb = ks * 32 + lg * 8;   // k element base for this lane
    bf16x8 ah[4], al[4], bh[4], bl[4];
#pragma unroll
    for (int mt = 0; mt < 4; mt++) {
      int row = mt * 16 + lr;
      int byte = row * 512 + ((kb * 2) ^ ((row & 7) << 4));
      ah[mt] = *(const bf16x8*)(sm + byte);
      al[mt] = *(const bf16x8*)(sm + 32768 + byte);
    }
#pragma unroll
    for (int nt = 0; nt < 4; nt++) {
      int col = nbase + nt * 16 + lr;
      bh[nt] = *(const bf16x8*)(w2t_hi + (size_t)col * HID + kb);
      bl[nt] = *(const bf16x8*)(w2t_lo + (size_t)col * HID + kb);
    }
#pragma unroll
    for (int mt = 0; mt < 4; mt++)
#pragma unroll
      for (int nt = 0; nt < 4; nt++) {
        acc[mt][nt] = __builtin_amdgcn_mfma_f32_16x16x32_bf16(ah[mt], bh[nt], acc[mt][nt], 0, 0, 0);
        acc[mt][nt] = __builtin_amdgcn_mfma_f32_16x16x32_bf16(ah[mt], bl[nt], acc[mt][nt], 0, 0, 0);
        acc[mt][nt] = __builtin_amdgcn_mfma_f32_16x16x32_bf16(al[mt], bh[nt], acc[mt][nt], 0, 0, 0);
      }
  }
  __syncthreads();   // all hs reads done; safe to overwrite with OUT

  // ---- spill frags to LDS OUT (2-way-max swizzle on col bit4) ----
  float* OUT = (float*)sm;
#pragma unroll
  for (int mt = 0; mt < 4; mt++)
#pragma unroll
    for (int nt = 0; nt < 4; nt++)
#pragma unroll
      for (int r = 0; r < 4; r++) {
        int row = mt * 16 + lg * 4 + r;   // C/D: row = (lane>>4)*4 + reg
        int col = nbase + nt * 16 + lr;   // C/D: col = lane&15
        int c2 = col ^ (((row >> 2) & 1) << 4);
        OUT[row * HID + c2] = acc[mt][nt][r];
      }
  __syncthreads();

  // ---- segmented max along edges; thread = one output column ----
  const int j = tid;
  const float b2j = b2[j];
  int prevd = sdst[0];
  int segstart = 0;
  float run = -INFINITY;
  for (int e = 0; e < 64; e++) {
    int d = sdst[e];                     // block-uniform branch
    if (d != prevd) {
      unsigned int enc = enc_f32(run + b2j);
      unsigned int* p = agg + (size_t)prevd * HID + j;
      if (segstart == 0) atomicMax(p, enc);  // open-left segment
      else *p = enc;                          // interior: exclusive to tile
      run = -INFINITY;
      segstart = e;
      prevd = d;
    }
    run = fmaxf(run, OUT[e * HID + (j ^ (((e >> 2) & 1) << 4))]);
  }
  atomicMax(agg + (size_t)prevd * HID + j, enc_f32(run + b2j));
}

// ---------------- decode monotone-uint -> float ----------------
__global__ __launch_bounds__(256) void decode_kernel(
    const unsigned int* __restrict__ agg, float* __restrict__ X) {
  int i = blockIdx.x * 256 + threadIdx.x;
  unsigned int u = agg[i];
  float f;
  if (u == 0u) {
    f = 0.f;  // no in-edges -> 0 (matches where(isfinite, agg, 0))
  } else {
    unsigned int bits = (u & 0x80000000u) ? (u ^ 0x80000000u) : ~u;
    f = __uint_as_float(bits);
  }
  X[i] = f;
}

// ---------------- per-graph mean/max pooling ----------------
__device__ __forceinline__ int lower_bound_i(const int* __restrict__ arr, int n, int val) {
  int lo = 0, hi = n;
  while (lo < hi) {
    int mid = (lo + hi) >> 1;
    if (arr[mid] < val) lo = mid + 1; else hi = mid;
  }
  return lo;
}

__global__ __launch_bounds__(256) void pool_kernel(
    const float* __restrict__ X, const int* __restrict__ batch,
    float* __restrict__ GP) {
  const int g = blockIdx.x;
  const int j = threadIdx.x;
  int s = lower_bound_i(batch, N_NODES, g);
  int e = lower_bound_i(batch, N_NODES, g + 1);
  float sum = 0.f, mx = -INFINITY;
  for (int i = s; i < e; i++) {
    float v = X[(size_t)i * HID + j];
    sum += v;
    mx = fmaxf(mx, v);
  }
  int cnt = e - s;
  GP[g * (2 * HID) + j] = sum / fmaxf((float)cnt, 1.f);
  GP[g * (2 * HID) + HID + j] = (cnt > 0) ? mx : 0.f;
}

// ---------------- graph-level MLP head (fp32 throughout) ----------------
__global__ __launch_bounds__(256) void mlp_kernel(
    const float* __restrict__ GP,
    const float* __restrict__ wc1, const float* __restrict__ bc1,
    const float* __restrict__ wc2, const float* __restrict__ bc2,
    const float* __restrict__ wc3, const float* __restrict__ bc3,
    float* __restrict__ out) {
  const int g = blockIdx.x;
  const int tid = threadIdx.x;
  __shared__ float gs[2 * HID];
  __shared__ float h1[HID];
  __shared__ float h2[64];
  gs[tid] = GP[g * (2 * HID) + tid];
  gs[tid + HID] = GP[g * (2 * HID) + HID + tid];
  __syncthreads();
  float acc = bc1[tid];
  for (int k = 0; k < 2 * HID; k++) acc = fmaf(gs[k], wc1[k * HID + tid], acc);
  h1[tid] = fmaxf(acc, 0.f);
  __syncthreads();
  if (tid < 64) {
    float a2 = bc2[tid];
    for (int k = 0; k < HID; k++) a2 = fmaf(h1[k], wc2[k * 64 + tid], a2);
    h2[tid] = fmaxf(a2, 0.f);
  }
  __syncthreads();
  if (tid == 0) {
    float a3 = bc3[0];
    for (int k = 0; k < 64; k++) a3 = fmaf(h2[k], wc3[k], a3);
    out[g] = a3;
  }
}

extern "C" void kernel_launch(void* const* d_in, const int* in_sizes, int n_in,
                              void* d_out, int out_size, void* d_ws, size_t ws_size,
                              hipStream_t stream) {
  const float* x      = (const float*)d_in[0];
  const int*   ei     = (const int*)d_in[1];
  const int*   batch  = (const int*)d_in[2];
  const float* w1[3]  = {(const float*)d_in[3], (const float*)d_in[7],  (const float*)d_in[11]};
  const float* b1[3]  = {(const float*)d_in[4], (const float*)d_in[8],  (const float*)d_in[12]};
  const float* w2[3]  = {(const float*)d_in[5], (const float*)d_in[9],  (const float*)d_in[13]};
  const float* b2[3]  = {(const float*)d_in[6], (const float*)d_in[10], (const float*)d_in[14]};
  const float* wc1 = (const float*)d_in[15];
  const float* bc1 = (const float*)d_in[16];
  const float* wc2 = (const float*)d_in[17];
  const float* bc2 = (const float*)d_in[18];
  const float* wc3 = (const float*)d_in[19];
  const float* bc3 = (const float*)d_in[20];
  float* out = (float*)d_out;

  char* ws = (char*)d_ws;
  size_t off = 0;
  auto walloc = [&](size_t bytes) -> void* {
    void* p = ws + off;
    off += (bytes + 255) & ~(size_t)255;
    return p;
  };
  const size_t nh_bytes = (size_t)N_NODES * HID * sizeof(float);
  float*          A       = (float*)walloc(nh_bytes);
  float*          Bm      = (float*)walloc(nh_bytes);
  float*          X       = (float*)walloc(nh_bytes);
  unsigned int*   AGG     = (unsigned int*)walloc(nh_bytes);
  float*          GP      = (float*)walloc((size_t)N_GRAPHS * 2 * HID * sizeof(float));
  int*            deg     = (int*)walloc((size_t)N_NODES * sizeof(int));
  int*            cursor  = (int*)walloc((size_t)N_NODES * sizeof(int));
  int*            csr_src = (int*)walloc((size_t)N_EDGES * sizeof(int));
  int*            csr_dst = (int*)walloc((size_t)N_EDGES * sizeof(int));
  unsigned short* w2t_hi  = (unsigned short*)walloc((size_t)HID * HID * sizeof(unsigned short));
  unsigned short* w2t_lo  = (unsigned short*)walloc((size_t)HID * HID * sizeof(unsigned short));
  (void)ws_size; (void)in_sizes; (void)n_in; (void)out_size;

  // ---- build CSR (by dst) once; max-agg is order-independent ----
  hipMemsetAsync(deg, 0, N_NODES * sizeof(int), stream);
  hist_kernel<<<(N_EDGES + 255) / 256, 256, 0, stream>>>(ei, deg);
  scan_kernel<<<1, 256, 0, stream>>>(deg, cursor);
  scatter_kernel<<<(N_EDGES + 255) / 256, 256, 0, stream>>>(ei, cursor, csr_src, csr_dst);

  for (int l = 0; l < 3; l++) {
    if (l == 0)
      node_ab_kernel<56><<<N_NODES / 32, 256, 0, stream>>>(x, w1[0], b1[0], A, Bm);
    else
      node_ab_kernel<256><<<N_NODES / 32, 256, 0, stream>>>(X, w1[l], b1[l], A, Bm);
    conv_w2_kernel<<<HID, HID, 0, stream>>>(w2[l], w2t_hi, w2t_lo);
    hipMemsetAsync(AGG, 0, nh_bytes, stream);
    edge_mfma_kernel<<<N_EDGES / 64, 256, 0, stream>>>(csr_src, csr_dst, A, Bm,
                                                       w2t_hi, w2t_lo, b2[l], AGG);
    decode_kernel<<<(N_NODES * HID) / 256, 256, 0, stream>>>(AGG, X);
  }
  pool_kernel<<<N_GRAPHS, 256, 0, stream>>>(X, batch, GP);
  mlp_kernel<<<N_GRAPHS, 256, 0, stream>>>(GP, wc1, bc1, wc2, bc2, wc3, bc3, out);
}

// Round 4
// 1169.839 us; speedup vs baseline: 10.2133x; 1.2654x over previous
//
#include <hip/hip_runtime.h>

#define N_NODES 20000
#define N_EDGES 320000
#define N_GRAPHS 64
#define HID 256
#define EB 48                               // edges per tile
#define NB ((N_EDGES + EB - 1) / EB)        // 6667 blocks
#define E_PAD (NB * EB)                     // 320016 (16 pad edges -> sentinel node)
#define SENT N_NODES                        // sentinel node id (extra padded row)

typedef __attribute__((ext_vector_type(8))) short bf16x8;
typedef __attribute__((ext_vector_type(4))) float f32x4;

// ---------------- helpers ----------------
__device__ __forceinline__ unsigned short bf16_rne(float f) {
  unsigned u = __float_as_uint(f);
  u = u + 0x7FFFu + ((u >> 16) & 1u);
  return (unsigned short)(u >> 16);
}

__device__ __forceinline__ unsigned int enc_f32(float v) {
  unsigned int bits = __float_as_uint(v);
  return (bits & 0x80000000u) ? ~bits : (bits | 0x80000000u);
}

__device__ __forceinline__ float dec_u32(unsigned int u) {
  if (u == 0u) return 0.f;   // never-written -> no in-edges -> 0
  unsigned int bits = (u & 0x80000000u) ? (u ^ 0x80000000u) : ~u;
  return __uint_as_float(bits);
}

// ---------------- CSR build (once per launch) ----------------
__global__ __launch_bounds__(256) void hist_kernel(const int* __restrict__ ei,
                                                   int* __restrict__ deg) {
  int e = blockIdx.x * 256 + threadIdx.x;
  if (e < N_EDGES) atomicAdd(&deg[ei[N_EDGES + e]], 1);
}

__global__ __launch_bounds__(256) void scan_kernel(const int* __restrict__ deg,
                                                   int* __restrict__ cursor) {
  __shared__ int part[256];
  const int tid = threadIdx.x;
  const int CH = (N_NODES + 255) / 256;
  int s = tid * CH;
  int e = s + CH; if (e > N_NODES) e = N_NODES; if (s > N_NODES) s = N_NODES;
  int sum = 0;
  for (int i = s; i < e; i++) sum += deg[i];
  part[tid] = sum;
  __syncthreads();
  for (int off = 1; off < 256; off <<= 1) {
    int v = (tid >= off) ? part[tid - off] : 0;
    __syncthreads();
    part[tid] += v;
    __syncthreads();
  }
  int prefix = (tid == 0) ? 0 : part[tid - 1];
  for (int i = s; i < e; i++) {
    cursor[i] = prefix;
    prefix += deg[i];
  }
}

__global__ __launch_bounds__(256) void scatter_kernel(const int* __restrict__ ei,
                                                      int* __restrict__ cursor,
                                                      int* __restrict__ csr_src,
                                                      int* __restrict__ csr_dst) {
  int e = blockIdx.x * 256 + threadIdx.x;
  if (e < N_EDGES) {
    int s = ei[e], d = ei[N_EDGES + e];
    int pos = atomicAdd(&cursor[d], 1);
    csr_src[pos] = s;
    csr_dst[pos] = d;
  }
}

__global__ void pad_kernel(int* __restrict__ csr_src, int* __restrict__ csr_dst) {
  int i = threadIdx.x;
  if (i < E_PAD - N_EDGES) {
    csr_src[N_EDGES + i] = SENT;
    csr_dst[N_EDGES + i] = SENT;
  }
}

// ---------------- per-node A/B precompute ----------------
// A = x @ (w1_top - w1_bot) + b1 ; B = x @ w1_bot
__global__ __launch_bounds__(256) void node_ab_l0_kernel(
    const float* __restrict__ x,
    const float* __restrict__ w1, const float* __restrict__ b1,
    float* __restrict__ A, float* __restrict__ B) {
  const int DIN = 56;
  __shared__ float xs[32 * DIN];
  const int node0 = blockIdx.x * 32;
  const int j = threadIdx.x;
  for (int t = threadIdx.x; t < 32 * DIN; t += 256) {
    int r = t / DIN, c = t - r * DIN;
    int node = node0 + r;
    xs[t] = (node < N_NODES) ? x[node * DIN + c] : 0.f;
  }
  __syncthreads();
  float accA[32], accB[32];
#pragma unroll
  for (int i = 0; i < 32; i++) { accA[i] = 0.f; accB[i] = 0.f; }
  for (int k = 0; k < DIN; k++) {
    float wt = w1[k * HID + j];
    float wb = w1[(k + DIN) * HID + j];
    float wa = wt - wb;
#pragma unroll
    for (int i = 0; i < 32; i++) {
      float xv = xs[i * DIN + k];
      accA[i] = fmaf(xv, wa, accA[i]);
      accB[i] = fmaf(xv, wb, accB[i]);
    }
  }
  float bj = b1[j];
  for (int i = 0; i < 32; i++) {
    int node = node0 + i;
    if (node < N_NODES) {
      A[node * HID + j] = accA[i] + bj;
      B[node * HID + j] = accB[i];
    }
  }
}

// layers 1/2: input is AGG (monotone-uint), decoded inline
__global__ __launch_bounds__(256) void node_ab_h_kernel(
    const unsigned int* __restrict__ agg,
    const float* __restrict__ w1, const float* __restrict__ b1,
    float* __restrict__ A, float* __restrict__ B) {
  __shared__ float xs[32 * HID];
  const int node0 = blockIdx.x * 32;
  const int j = threadIdx.x;
  for (int t = threadIdx.x; t < 32 * HID / 4; t += 256) {
    int r = t >> 6, c4 = t & 63;
    int node = node0 + r;
    float4 f = {0.f, 0.f, 0.f, 0.f};
    if (node < N_NODES) {
      uint4 u = *(const uint4*)(agg + (size_t)node * HID + c4 * 4);
      f.x = dec_u32(u.x); f.y = dec_u32(u.y); f.z = dec_u32(u.z); f.w = dec_u32(u.w);
    }
    *(float4*)(xs + r * HID + c4 * 4) = f;
  }
  __syncthreads();
  float accA[32], accB[32];
#pragma unroll
  for (int i = 0; i < 32; i++) { accA[i] = 0.f; accB[i] = 0.f; }
  for (int k = 0; k < HID; k++) {
    float wt = w1[k * HID + j];
    float wb = w1[(k + HID) * HID + j];
    float wa = wt - wb;
#pragma unroll
    for (int i = 0; i < 32; i++) {
      float xv = xs[i * HID + k];
      accA[i] = fmaf(xv, wa, accA[i]);
      accB[i] = fmaf(xv, wb, accB[i]);
    }
  }
  float bj = b1[j];
  for (int i = 0; i < 32; i++) {
    A[(size_t)(node0 + i) * HID + j] = accA[i] + bj;
    B[(size_t)(node0 + i) * HID + j] = accB[i];
  }
}

// ---------------- w2 transpose + hi/lo bf16 split ----------------
__global__ __launch_bounds__(256) void conv_w2_kernel(
    const float* __restrict__ w2,
    unsigned short* __restrict__ w2t_hi, unsigned short* __restrict__ w2t_lo) {
  int j = blockIdx.x;
  int k = threadIdx.x;
  float v = w2[k * HID + j];
  unsigned short hi = bf16_rne(v);
  float rem = v - __uint_as_float(((unsigned)hi) << 16);
  w2t_hi[j * HID + k] = hi;
  w2t_lo[j * HID + k] = bf16_rne(rem);
}

// ---------------- edge MLP (MFMA hi/lo) + segmented max ----------------
__global__ __launch_bounds__(256, 3) void edge_mfma_kernel(
    const int* __restrict__ csr_src, const int* __restrict__ csr_dst,
    const float* __restrict__ A, const float* __restrict__ Bm,
    const unsigned short* __restrict__ w2t_hi,
    const unsigned short* __restrict__ w2t_lo,
    const float* __restrict__ b2,
    unsigned int* __restrict__ agg) {
  // LDS: hs_hi bf16[EB][256] @0 (24KB), hs_lo @24576 (24KB); OUT f32[EB][256] aliases @0 (48KB)
  __shared__ char sm[EB * 512 * 2];
  __shared__ int sdst[EB];
  __shared__ int ssrc[EB];
  const int tid = threadIdx.x;
  const int e0 = blockIdx.x * EB;
  if (tid < EB) { sdst[tid] = csr_dst[e0 + tid]; ssrc[tid] = csr_src[e0 + tid]; }
  __syncthreads();
  const int lane = tid & 63;
  const int wid = tid >> 6;

  // ---- gather + relu + hi/lo split: wave-per-rep, float4 per lane ----
#pragma unroll 4
  for (int rr = 0; rr < EB / 4; rr++) {
    int rep = wid * (EB / 4) + rr;
    int s = ssrc[rep], d = sdst[rep];
    float4 av = *(const float4*)(A + (size_t)d * HID + lane * 4);
    float4 bv = *(const float4*)(Bm + (size_t)s * HID + lane * 4);
    float va[4], vb[4];
    *(float4*)va = av; *(float4*)vb = bv;
    unsigned long long hp = 0, lp = 0;
#pragma unroll
    for (int i = 0; i < 4; i++) {
      float v = fmaxf(va[i] + vb[i], 0.f);
      unsigned hu = bf16_rne(v);
      float rem = v - __uint_as_float(hu << 16);
      unsigned lu = bf16_rne(rem);
      hp |= (unsigned long long)hu << (16 * i);
      lp |= (unsigned long long)lu << (16 * i);
    }
    int byte = rep * 512 + ((lane * 8) ^ ((rep & 7) << 4));
    *(unsigned long long*)(sm + byte) = hp;
    *(unsigned long long*)(sm + EB * 512 + byte) = lp;
  }
  __syncthreads();

  // ---- MFMA: wave wid computes OUT[0:EB][wid*64 .. +64) ----
  const int nbase = wid * 64;
  const int lr = lane & 15;
  const int lg = lane >> 4;
  f32x4 acc[3][4];
#pragma unroll
  for (int mt = 0; mt < 3; mt++)
#pragma unroll
    for (int nt = 0; nt < 4; nt++) acc[mt][nt] = (f32x4){0.f, 0.f, 0.f, 0.f};

#pragma unroll
  for (int ks = 0; ks < 8; ks++) {
    const int kb = ks * 32 + lg * 8;
    bf16x8 ah[3], al[3], bh[4], bl[4];
#pragma unroll
    for (int mt = 0; mt < 3; mt++) {
      int row = mt * 16 + lr;
      int byte = row * 512 + ((kb * 2) ^ ((row & 7) << 4));
      ah[mt] = *(const bf16x8*)(sm + byte);
      al[mt] = *(const bf16x8*)(sm + EB * 512 + byte);
    }
#pragma unroll
    for (int nt = 0; nt < 4; nt++) {
      int col = nbase + nt * 16 + lr;
      bh[nt] = *(const bf16x8*)(w2t_hi + (size_t)col * HID + kb);
      bl[nt] = *(const bf16x8*)(w2t_lo + (size_t)col * HID + kb);
    }
#pragma unroll
    for (int mt = 0; mt < 3; mt++)
#pragma unroll
      for (int nt = 0; nt < 4; nt++) {
        acc[mt][nt] = __builtin_amdgcn_mfma_f32_16x16x32_bf16(ah[mt], bh[nt], acc[mt][nt], 0, 0, 0);
        acc[mt][nt] = __builtin_amdgcn_mfma_f32_16x16x32_bf16(ah[mt], bl[nt], acc[mt][nt], 0, 0, 0);
        acc[mt][nt] = __builtin_amdgcn_mfma_f32_16x16x32_bf16(al[mt], bh[nt], acc[mt][nt], 0, 0, 0);
      }
  }
  __syncthreads();

  // ---- spill frags to LDS OUT (col bit4 swizzle keyed on row bit2) ----
  float* OUT = (float*)sm;
#pragma unroll
  for (int mt = 0; mt < 3; mt++)
#pragma unroll
    for (int nt = 0; nt < 4; nt++)
#pragma unroll
      for (int r = 0; r < 4; r++) {
        int row = mt * 16 + lg * 4 + r;
        int col = nbase + nt * 16 + lr;
        int c2 = col ^ (((row >> 2) & 1) << 4);
        OUT[row * HID + c2] = acc[mt][nt][r];
      }
  __syncthreads();

  // ---- segmented max along edges; thread = one output column ----
  const int j = tid;
  const float b2j = b2[j];
  int prevd = sdst[0];
  int segstart = 0;
  float run = -INFINITY;
  for (int e = 0; e < EB; e++) {
    int d = sdst[e];                     // block-uniform branch
    if (d != prevd) {
      unsigned int enc = enc_f32(run + b2j);
      unsigned int* p = agg + (size_t)prevd * HID + j;
      if (segstart == 0) atomicMax(p, enc);  // open-left segment
      else *p = enc;                          // interior: exclusive to tile
      run = -INFINITY;
      segstart = e;
      prevd = d;
    }
    run = fmaxf(run, OUT[e * HID + (j ^ (((e >> 2) & 1) << 4))]);
  }
  atomicMax(agg + (size_t)prevd * HID + j, enc_f32(run + b2j));
}

// ---------------- per-graph mean/max pooling (decode inline) -------------
__device__ __forceinline__ int lower_bound_i(const int* __restrict__ arr, int n, int val) {
  int lo = 0, hi = n;
  while (lo < hi) {
    int mid = (lo + hi) >> 1;
    if (arr[mid] < val) lo = mid + 1; else hi = mid;
  }
  return lo;
}

__global__ __launch_bounds__(256) void pool_kernel(
    const unsigned int* __restrict__ agg, const int* __restrict__ batch,
    float* __restrict__ GP) {
  const int g = blockIdx.x;
  const int j = threadIdx.x;
  int s = lower_bound_i(batch, N_NODES, g);
  int e = lower_bound_i(batch, N_NODES, g + 1);
  float sum = 0.f, mx = -INFINITY;
  for (int i = s; i < e; i++) {
    float v = dec_u32(agg[(size_t)i * HID + j]);
    sum += v;
    mx = fmaxf(mx, v);
  }
  int cnt = e - s;
  GP[g * (2 * HID) + j] = sum / fmaxf((float)cnt, 1.f);
  GP[g * (2 * HID) + HID + j] = (cnt > 0) ? mx : 0.f;
}

// ---------------- graph-level MLP head ----------------
__global__ __launch_bounds__(256) void mlp_kernel(
    const float* __restrict__ GP,
    const float* __restrict__ wc1, const float* __restrict__ bc1,
    const float* __restrict__ wc2, const float* __restrict__ bc2,
    const float* __restrict__ wc3, const float* __restrict__ bc3,
    float* __restrict__ out) {
  const int g = blockIdx.x;
  const int tid = threadIdx.x;
  __shared__ float gs[2 * HID];
  __shared__ float h1[HID];
  __shared__ float h2[64];
  gs[tid] = GP[g * (2 * HID) + tid];
  gs[tid + HID] = GP[g * (2 * HID) + HID + tid];
  __syncthreads();
  float acc = bc1[tid];
  for (int k = 0; k < 2 * HID; k++) acc = fmaf(gs[k], wc1[k * HID + tid], acc);
  h1[tid] = fmaxf(acc, 0.f);
  __syncthreads();
  if (tid < 64) {
    float a2 = bc2[tid];
    for (int k = 0; k < HID; k++) a2 = fmaf(h1[k], wc2[k * 64 + tid], a2);
    h2[tid] = fmaxf(a2, 0.f);
  }
  __syncthreads();
  if (tid == 0) {
    float a3 = bc3[0];
    for (int k = 0; k < 64; k++) a3 = fmaf(h2[k], wc3[k], a3);
    out[g] = a3;
  }
}

extern "C" void kernel_launch(void* const* d_in, const int* in_sizes, int n_in,
                              void* d_out, int out_size, void* d_ws, size_t ws_size,
                              hipStream_t stream) {
  const float* x      = (const float*)d_in[0];
  const int*   ei     = (const int*)d_in[1];
  const int*   batch  = (const int*)d_in[2];
  const float* w1[3]  = {(const float*)d_in[3], (const float*)d_in[7],  (const float*)d_in[11]};
  const float* b1[3]  = {(const float*)d_in[4], (const float*)d_in[8],  (const float*)d_in[12]};
  const float* w2[3]  = {(const float*)d_in[5], (const float*)d_in[9],  (const float*)d_in[13]};
  const float* b2[3]  = {(const float*)d_in[6], (const float*)d_in[10], (const float*)d_in[14]};
  const float* wc1 = (const float*)d_in[15];
  const float* bc1 = (const float*)d_in[16];
  const float* wc2 = (const float*)d_in[17];
  const float* bc2 = (const float*)d_in[18];
  const float* wc3 = (const float*)d_in[19];
  const float* bc3 = (const float*)d_in[20];
  float* out = (float*)d_out;

  char* ws = (char*)d_ws;
  size_t off = 0;
  auto walloc = [&](size_t bytes) -> void* {
    void* p = ws + off;
    off += (bytes + 255) & ~(size_t)255;
    return p;
  };
  const size_t nh_pad = (size_t)(N_NODES + 1) * HID;  // +1 sentinel row
  float*          A       = (float*)walloc(nh_pad * sizeof(float));
  float*          Bm      = (float*)walloc(nh_pad * sizeof(float));
  unsigned int*   AGG     = (unsigned int*)walloc(nh_pad * sizeof(unsigned int));
  float*          GP      = (float*)walloc((size_t)N_GRAPHS * 2 * HID * sizeof(float));
  int*            deg     = (int*)walloc((size_t)N_NODES * sizeof(int));
  int*            cursor  = (int*)walloc((size_t)N_NODES * sizeof(int));
  int*            csr_src = (int*)walloc((size_t)E_PAD * sizeof(int));
  int*            csr_dst = (int*)walloc((size_t)E_PAD * sizeof(int));
  unsigned short* w2t_hi  = (unsigned short*)walloc((size_t)HID * HID * sizeof(unsigned short));
  unsigned short* w2t_lo  = (unsigned short*)walloc((size_t)HID * HID * sizeof(unsigned short));
  (void)ws_size; (void)in_sizes; (void)n_in; (void)out_size;

  // ---- one-time: CSR build + pads ----
  hipMemsetAsync(deg, 0, N_NODES * sizeof(int), stream);
  hipMemsetAsync(A + (size_t)SENT * HID, 0, HID * sizeof(float), stream);
  hipMemsetAsync(Bm + (size_t)SENT * HID, 0, HID * sizeof(float), stream);
  hist_kernel<<<(N_EDGES + 255) / 256, 256, 0, stream>>>(ei, deg);
  scan_kernel<<<1, 256, 0, stream>>>(deg, cursor);
  scatter_kernel<<<(N_EDGES + 255) / 256, 256, 0, stream>>>(ei, cursor, csr_src, csr_dst);
  pad_kernel<<<1, 64, 0, stream>>>(csr_src, csr_dst);

  for (int l = 0; l < 3; l++) {
    if (l == 0)
      node_ab_l0_kernel<<<N_NODES / 32, 256, 0, stream>>>(x, w1[0], b1[0], A, Bm);
    else
      node_ab_h_kernel<<<N_NODES / 32, 256, 0, stream>>>(AGG, w1[l], b1[l], A, Bm);
    conv_w2_kernel<<<HID, HID, 0, stream>>>(w2[l], w2t_hi, w2t_lo);
    hipMemsetAsync(AGG, 0, nh_pad * sizeof(unsigned int), stream);
    edge_mfma_kernel<<<NB, 256, 0, stream>>>(csr_src, csr_dst, A, Bm,
                                             w2t_hi, w2t_lo, b2[l], AGG);
  }
  pool_kernel<<<N_GRAPHS, 256, 0, stream>>>(AGG, batch, GP);
  mlp_kernel<<<N_GRAPHS, 256, 0, stream>>>(GP, wc1, bc1, wc2, bc2, wc3, bc3, out);
}